// Round 3
// baseline (52.594 us; speedup 1.0000x reference)
//
#include <hip/hip_runtime.h>

#define B_DIM 32
#define T_DIM 4096
#define D_DIM 512
#define E_DIM 512
#define EPS_K 1e-7f
#define NGRP (T_DIM / 32)   // 128 score blocks per batch

// ---------------------------------------------------------------------------
// Kernel 1: yp[b,d] = sum_e y[b,e] * W[d,e]   (yp = y @ W^T)
// One wave per (b,d): lanes across e, coalesced float4 loads, butterfly.
// ---------------------------------------------------------------------------
__global__ __launch_bounds__(256) void yp_kernel(const float* __restrict__ y,
                                                 const float* __restrict__ W,
                                                 float* __restrict__ yp) {
    const int b    = blockIdx.y;
    const int wave = threadIdx.x >> 6;
    const int lane = threadIdx.x & 63;
    const int d    = blockIdx.x * 4 + wave;

    const float4* Wv = (const float4*)(W + (size_t)d * E_DIM);
    const float4* yv = (const float4*)(y + (size_t)b * E_DIM);
    const float4 w0 = Wv[lane];
    const float4 w1 = Wv[lane + 64];
    const float4 y0 = yv[lane];
    const float4 y1 = yv[lane + 64];

    float p = w0.x * y0.x + w0.y * y0.y + w0.z * y0.z + w0.w * y0.w
            + w1.x * y1.x + w1.y * y1.y + w1.z * y1.z + w1.w * y1.w;
#pragma unroll
    for (int off = 32; off > 0; off >>= 1) p += __shfl_xor(p, off);

    if (lane == 0) yp[(size_t)b * D_DIM + d] = p;
}

// ---------------------------------------------------------------------------
// Kernel 2: a_raw[b,t] = exp(tanh(dot(x[b,t,:], yp[b,:]) + bias)) * mask[b,t]
// plus a per-block partial sum partials[b*NGRP + g] (fixed tree, no atomics).
// grid (NGRP, B), 256 thr = 4 waves; each wave handles 8 consecutive t.
// ---------------------------------------------------------------------------
__global__ __launch_bounds__(256) void score_kernel(const float* __restrict__ x,
                                                    const float* __restrict__ yp,
                                                    const float* __restrict__ bias,
                                                    const int* __restrict__ mask,
                                                    float* __restrict__ a_raw,
                                                    float* __restrict__ partials) {
    const int b    = blockIdx.y;
    const int wave = threadIdx.x >> 6;
    const int lane = threadIdx.x & 63;
    const int t0   = blockIdx.x * 32 + wave * 8;

    const float4* ypv = (const float4*)(yp + (size_t)b * D_DIM);
    const float4 w0 = ypv[lane];
    const float4 w1 = ypv[lane + 64];

    const float4* xv = (const float4*)(x + ((size_t)b * T_DIM + (size_t)t0) * D_DIM);

    // Issue all 16 streaming loads first (64 VGPRs of x in flight).
    float4 xa[8], xb[8];
#pragma unroll
    for (int i = 0; i < 8; ++i) {
        xa[i] = xv[i * (D_DIM / 4) + lane];
        xb[i] = xv[i * (D_DIM / 4) + lane + 64];
    }

    float p[8];
#pragma unroll
    for (int i = 0; i < 8; ++i) {
        p[i] = xa[i].x * w0.x + xa[i].y * w0.y + xa[i].z * w0.z + xa[i].w * w0.w
             + xb[i].x * w1.x + xb[i].y * w1.y + xb[i].z * w1.z + xb[i].w * w1.w;
    }

    // 8 independent butterfly reduces, interleaved per step for ILP.
#pragma unroll
    for (int off = 32; off > 0; off >>= 1) {
#pragma unroll
        for (int i = 0; i < 8; ++i) p[i] += __shfl_xor(p[i], off);
    }

    // Lanes 0..7 finalize row t0+lane (coalesced 32B store).
    float a = 0.f;
    if (lane < 8) {
        float s = (lane == 0) ? p[0] : (lane == 1) ? p[1] : (lane == 2) ? p[2]
                : (lane == 3) ? p[3] : (lane == 4) ? p[4] : (lane == 5) ? p[5]
                : (lane == 6) ? p[6] : p[7];
        const int t = t0 + lane;
        const float e = expf(tanhf(s + bias[0]));
        a = mask[(size_t)b * T_DIM + t] ? e : 0.f;
        a_raw[(size_t)b * T_DIM + t] = a;
    }

    // Block partial sum: butterfly (lanes >=8 contribute 0) + fixed LDS tree.
    float ws = a;
#pragma unroll
    for (int off = 32; off > 0; off >>= 1) ws += __shfl_xor(ws, off);

    __shared__ float ls[4];
    if (lane == 0) ls[wave] = ws;
    __syncthreads();
    if (threadIdx.x == 0)
        partials[(size_t)b * NGRP + blockIdx.x] = (ls[0] + ls[1]) + (ls[2] + ls[3]);
}

// ---------------------------------------------------------------------------
// Kernel 3: out[b,t] = a_raw[b,t] / (sum_b + EPS)
// grid (B, 8), 128 thr. Wave 0 reduces the batch's 128 partials in a fixed
// tree (bitwise identical across the batch's 8 blocks); all threads scale
// 512 t's (1 float4 each).
// ---------------------------------------------------------------------------
__global__ __launch_bounds__(128) void norm_kernel(const float* __restrict__ a_raw,
                                                   const float* __restrict__ partials,
                                                   float* __restrict__ out) {
    const int b = blockIdx.x;
    const int c = blockIdx.y;
    __shared__ float inv_s;

    if (threadIdx.x < 64) {
        const int lane = threadIdx.x;
        const float* pp = partials + (size_t)b * NGRP;
        float s = pp[2 * lane] + pp[2 * lane + 1];
#pragma unroll
        for (int off = 32; off > 0; off >>= 1) s += __shfl_xor(s, off);
        if (lane == 0) inv_s = 1.0f / (s + EPS_K);
    }
    __syncthreads();

    const float inv = inv_s;
    const int idx = c * 128 + threadIdx.x;  // float4 index within the batch row
    const float4 v = ((const float4*)(a_raw + (size_t)b * T_DIM))[idx];
    ((float4*)(out + (size_t)b * T_DIM))[idx] =
        make_float4(v.x * inv, v.y * inv, v.z * inv, v.w * inv);
}

// ---------------------------------------------------------------------------
extern "C" void kernel_launch(void* const* d_in, const int* in_sizes, int n_in,
                              void* d_out, int out_size, void* d_ws, size_t ws_size,
                              hipStream_t stream) {
    const float* x    = (const float*)d_in[0];  // [B,T,D]
    const float* y    = (const float*)d_in[1];  // [B,E]
    const float* W    = (const float*)d_in[2];  // [D,E]
    const float* bias = (const float*)d_in[3];  // [1]
    const int*   mask = (const int*)d_in[4];    // [B,T] (bool -> int32 per harness)
    float* out = (float*)d_out;                 // [B,T]

    float* yp       = (float*)d_ws;                  // B*D floats    = 64 KB
    float* a_raw    = yp + B_DIM * D_DIM;            // B*T floats    = 512 KB
    float* partials = a_raw + B_DIM * T_DIM;         // B*NGRP floats = 16 KB

    yp_kernel<<<dim3(D_DIM / 4, B_DIM), 256, 0, stream>>>(y, W, yp);
    score_kernel<<<dim3(NGRP, B_DIM), 256, 0, stream>>>(x, yp, bias, mask, a_raw, partials);
    norm_kernel<<<dim3(B_DIM, 8), 128, 0, stream>>>(a_raw, partials, out);
}